// Round 1
// baseline (216.960 us; speedup 1.0000x reference)
//
#include <hip/hip_runtime.h>
#include <math.h>

#define D1 768
#define D2R 385
#define NF 295680   // 768*385
#define KNUM 4
#define NB 8
#define NC 256
#define TWOPI_768 0.008181230868723419f

// ---------------- ws layout (bytes) --------------------------------------
// specB  bf16 [4][448 c-rows][1536 k]   @ 0          (6,291,456 B)  B^T stage A
// Atw    bf16 [2][768 m][1536 k]        @ 6,291,456  (4,718,592 B)  A stage A
// Ya     bf16 [4][768 m][800 k]         @ 11,010,048 (4,915,200 B)  A stage B
// T      bf16 [768 n][800 k]            @ 15,925,248 (1,228,800 B)  B^T stage B
// SW     f32  [4][768][768]             @ 0          (9,437,184 B)  overlays specB+Atw (dead)
// wBF    bf16 [8][16][9][256][16]       @ 9,437,184  (9,437,184 B)  overlays Ya+T (dead)
#define ATW_U32 1572864u
#define YA_U32 2752512u
#define T_U32 3981312u
#define SPECB_K_U32 344064u  // 448*768 uints per k
#define WBF_BYTE 9437184u

typedef __attribute__((ext_vector_type(8))) short short8;
typedef __attribute__((ext_vector_type(16))) float f32x16;
union U4S8 { unsigned int u[4]; uint4 u4; short8 s8; };

static __device__ __forceinline__ unsigned int f2bf(float f) {
  unsigned int u = __float_as_uint(f);
  return (u + 0x7fffu + ((u >> 16) & 1u)) >> 16;  // RNE, no NaN inputs
}

// ---------------- prep: scatter + twiddle matrices + zero pads -----------
__global__ __launch_bounds__(256) void prep_kernel(
    const float* __restrict__ dw, const int* __restrict__ fh,
    const int* __restrict__ fw, unsigned int* __restrict__ ws) {
  long i = (long)blockIdx.x * 256 + threadIdx.x;  // grid 11364
  if (i < 1182720) {  // scatter: dft_weight -> bf16 B^T spectrum
    int k = (int)(i / NF);
    int r = (int)(i - (long)k * NF);
    const float2 v = ((const float2*)dw)[i];
    int h = fh[r], c = fw[r];
    ws[(size_t)k * SPECB_K_U32 + (size_t)c * 768 + h] =
        f2bf(v.x) | (f2bf(v.y) << 16);
    return;
  }
  long j = i - 1182720;
  if (j < 1179648) {  // Atw: A_re/A_im [768 m][1536 k=2h]
    int ri = (int)(j / 589824);
    int rem = (int)(j - (long)ri * 589824);
    int m = rem / 768, h = rem - (rem / 768) * 768;
    int idx = (h * m) % 768;
    float s, c;
    sincosf((float)idx * TWOPI_768, &s, &c);
    unsigned lo, hi;
    if (ri == 0) { lo = f2bf(c); hi = f2bf(-s); }
    else         { lo = f2bf(s); hi = f2bf(c); }
    ws[ATW_U32 + j] = lo | (hi << 16);
  } else if (j < 1486848) {  // T^T [768 n][800 k=2c]
    long p = j - 1179648;
    int n = (int)(p / 400), cc = (int)(p - (p / 400) * 400);
    unsigned v = 0;
    if (cc <= 384) {
      float wgt = (cc == 0 || cc == 384) ? 1.6954210069444445e-6f
                                         : 3.390842013888889e-6f;
      int idx = (cc * n) % 768;
      float s, c;
      sincosf((float)idx * TWOPI_768, &s, &c);
      v = f2bf(wgt * c) | (f2bf(-wgt * s) << 16);
    }
    ws[T_U32 + (size_t)n * 400 + cc] = v;
  } else if (j < 1680384) {  // specB zero rows 385..447
    long p = j - 1486848;
    int k = (int)(p / 48384);
    long r = p - (long)k * 48384;
    int row = 385 + (int)(r / 768);
    int col = (int)(r - (r / 768) * 768);
    ws[(size_t)k * SPECB_K_U32 + (size_t)row * 768 + col] = 0u;
  } else if (j < 1726464) {  // Ya zero cols 770..799
    long p = j - 1680384;
    int k = (int)(p / 11520);
    long r = p - (long)k * 11520;
    int m = (int)(r / 15), jj = (int)(r - (r / 15) * 15);
    ws[YA_U32 + (size_t)k * 307200 + (size_t)m * 400 + 385 + jj] = 0u;
  }
}

// ---------------- fftA: dbuf bf16 MFMA GEMM, M=768 N=448(385) K=1536 -----
__global__ __launch_bounds__(256) void fftA_kernel(
    const unsigned short* __restrict__ Atw,
    const unsigned short* __restrict__ specB,
    unsigned short* __restrict__ Ya) {
  __shared__ __align__(16) unsigned short Al[2][64 * 40], Bl[2][64 * 40];
  int t = threadIdx.x;
  int mt = blockIdx.x, nt = blockIdx.y, z = blockIdx.z;
  int ri = z & 1, k = z >> 1;
  const unsigned short* Ag =
      Atw + (size_t)ri * 1179648 + (size_t)(mt * 64) * 1536;
  const unsigned short* Bg =
      specB + (size_t)k * 688128 + (size_t)(nt * 64) * 1536;
  int rowS = t >> 2, q = t & 3;
  int lane = t & 63, w = t >> 6;
  int moff = (w & 1) * 32, noff = (w >> 1) * 32;
  int lm = lane & 31, half = lane >> 5;
  int wr = rowS * 40 + q * 8;
  int ao = (moff + lm) * 40 + half * 8;
  int bo = (noff + lm) * 40 + half * 8;

  f32x16 acc;
#pragma unroll
  for (int r = 0; r < 16; ++r) acc[r] = 0.f;

  uint4 av = *(const uint4*)(Ag + (size_t)rowS * 1536 + q * 8);
  uint4 bv = *(const uint4*)(Bg + (size_t)rowS * 1536 + q * 8);
  *(uint4*)&Al[0][wr] = av;
  *(uint4*)&Bl[0][wr] = bv;
  __syncthreads();

  for (int kb = 0; kb < 48; ++kb) {
    bool more = (kb < 47);
    if (more) {
      av = *(const uint4*)(Ag + (size_t)rowS * 1536 + (kb + 1) * 32 + q * 8);
      bv = *(const uint4*)(Bg + (size_t)rowS * 1536 + (kb + 1) * 32 + q * 8);
    }
    const unsigned short* Ab = Al[kb & 1];
    const unsigned short* Bb = Bl[kb & 1];
#pragma unroll
    for (int kk2 = 0; kk2 < 2; ++kk2) {
      short8 a8 = *(const short8*)&Ab[ao + kk2 * 16];
      short8 b8 = *(const short8*)&Bb[bo + kk2 * 16];
      acc = __builtin_amdgcn_mfma_f32_32x32x16_bf16(a8, b8, acc, 0, 0, 0);
    }
    if (more) {
      *(uint4*)&Al[(kb + 1) & 1][wr] = av;
      *(uint4*)&Bl[(kb + 1) & 1][wr] = bv;
    }
    __syncthreads();
  }

  int c = nt * 64 + noff + lm;
  if (c < D2R) {
    unsigned short* Yk = Ya + (size_t)k * 614400;
    int mb = mt * 64 + moff + 4 * half;
#pragma unroll
    for (int reg = 0; reg < 16; ++reg) {
      int m = mb + (reg & 3) + 8 * (reg >> 2);
      Yk[(size_t)m * 800 + 2 * c + ri] = (unsigned short)f2bf(acc[reg]);
    }
  }
}

// ---------------- fftB: dbuf bf16 MFMA GEMM, M=768 N=768 K=800 -----------
__global__ __launch_bounds__(256) void fftB_kernel(
    const unsigned short* __restrict__ Ya, const unsigned short* __restrict__ T,
    float* __restrict__ SW) {
  __shared__ __align__(16) unsigned short Al[2][64 * 40], Bl[2][64 * 40];
  int t = threadIdx.x;
  int mt = blockIdx.x, nt = blockIdx.y, k = blockIdx.z;
  const unsigned short* Ag = Ya + (size_t)k * 614400 + (size_t)(mt * 64) * 800;
  const unsigned short* Bg = T + (size_t)(nt * 64) * 800;
  int rowS = t >> 2, q = t & 3;
  int lane = t & 63, w = t >> 6;
  int moff = (w & 1) * 32, noff = (w >> 1) * 32;
  int lm = lane & 31, half = lane >> 5;
  int wr = rowS * 40 + q * 8;
  int ao = (moff + lm) * 40 + half * 8;
  int bo = (noff + lm) * 40 + half * 8;

  f32x16 acc;
#pragma unroll
  for (int r = 0; r < 16; ++r) acc[r] = 0.f;

  uint4 av = *(const uint4*)(Ag + (size_t)rowS * 800 + q * 8);
  uint4 bv = *(const uint4*)(Bg + (size_t)rowS * 800 + q * 8);
  *(uint4*)&Al[0][wr] = av;
  *(uint4*)&Bl[0][wr] = bv;
  __syncthreads();

  for (int kb = 0; kb < 25; ++kb) {
    bool more = (kb < 24);
    if (more) {
      av = *(const uint4*)(Ag + (size_t)rowS * 800 + (kb + 1) * 32 + q * 8);
      bv = *(const uint4*)(Bg + (size_t)rowS * 800 + (kb + 1) * 32 + q * 8);
    }
    const unsigned short* Ab = Al[kb & 1];
    const unsigned short* Bb = Bl[kb & 1];
#pragma unroll
    for (int kk2 = 0; kk2 < 2; ++kk2) {
      short8 a8 = *(const short8*)&Ab[ao + kk2 * 16];
      short8 b8 = *(const short8*)&Bb[bo + kk2 * 16];
      acc = __builtin_amdgcn_mfma_f32_32x32x16_bf16(a8, b8, acc, 0, 0, 0);
    }
    if (more) {
      *(uint4*)&Al[(kb + 1) & 1][wr] = av;
      *(uint4*)&Bl[(kb + 1) & 1][wr] = bv;
    }
    __syncthreads();
  }

  float* SWk = SW + (size_t)k * 589824;
  int n = nt * 64 + noff + lm;
  int mb = mt * 64 + moff + 4 * half;
#pragma unroll
  for (int reg = 0; reg < 16; ++reg) {
    int m = mb + (reg & 3) + 8 * (reg >> 2);
    SWk[(size_t)m * 768 + n] = acc[reg];
  }
}

// ---------------- wprep v2: 1 block per SW row, LDS-staged coalesced -----
__global__ __launch_bounds__(256) void wprep_kernel(
    const float* __restrict__ ka, const float* __restrict__ SW,
    unsigned short* __restrict__ wBF) {
  __shared__ float rowL[4][768];
  int t = threadIdx.x;
  int row = blockIdx.x;  // grid 768: row = oc*3 + dy
  int oc = row / 3, dy = row - oc * 3;
  if (t < 192) {
#pragma unroll
    for (int k = 0; k < 4; ++k)
      *(float4*)&rowL[k][t * 4] =
          *(const float4*)(SW + (size_t)k * 589824 + (size_t)row * 768 + t * 4);
  }
  float att[8][4];
#pragma unroll
  for (int b = 0; b < 8; ++b)
#pragma unroll
    for (int k = 0; k < 4; ++k)
      att[b][k] = 0.5f / (1.f + expf(-ka[b * 4 + k]));
  __syncthreads();
  int icb = t >> 4, i = t & 15;
#pragma unroll
  for (int dx = 0; dx < 3; ++dx) {
    int col = icb * 48 + dx + 3 * i;
    float v0 = rowL[0][col], v1 = rowL[1][col], v2 = rowL[2][col],
          v3 = rowL[3][col];
    int s = dy * 3 + dx;
#pragma unroll
    for (int b = 0; b < 8; ++b) {
      float v = att[b][0] * v0 + att[b][1] * v1 + att[b][2] * v2 +
                att[b][3] * v3;
      wBF[(((size_t)(b * 16 + icb) * 9 + s) * 256 + oc) * 16 + i] =
          (unsigned short)f2bf(v);
    }
  }
}

// ---------------- conv v5: oc-split x4 -> 1024 blocks, 4 blocks/CU -------
// block = 64 oc x 2 py x 64 px; wave = 64 oc x 32 px (acc[2], 32 VGPR).
// Per-CU pipe totals identical to v4 (LDS reads, MFMA, wBF L2 fetch), but
// 16 waves/CU instead of 8 -> latency hiding. x re-read x4 oct (L2/L3).
__global__ __launch_bounds__(256, 4) void conv_mfma_kernel(
    const float* __restrict__ x, const unsigned short* __restrict__ wBF,
    float* __restrict__ out) {
  __shared__ __align__(16) unsigned char ldsX[2][4 * 66 * 48];
  int t = threadIdx.x;
  int pxt = blockIdx.x, oct = blockIdx.y, b = blockIdx.z;
  int py0 = pxt * 2, oc0 = oct * 64;
  int lane = t & 63, w = t >> 6;
  int pxq = w & 1, pxw = w >> 1;
  int n = lane & 31, half = lane >> 5;

  // zero halo cols (c=0,65; rows 0..3) in both buffers, once
  if (t < 192) {
    int buf = t / 96, r2 = t - buf * 96;
    int site = r2 / 12, word = r2 - site * 12;
    int r = site >> 1, c = (site & 1) ? 65 : 0;
    *(unsigned int*)(&ldsX[buf][(r * 66 + c) * 48 + word * 4]) = 0u;
  }

  f32x16 acc[2];
#pragma unroll
  for (int i = 0; i < 2; ++i)
#pragma unroll
    for (int r = 0; r < 16; ++r) acc[i][r] = 0.f;

  // x staging role
  int s_cq = t >> 5, s_r = (t >> 3) & 3, s_icp = t & 7;
  int iy = py0 - 1 + s_r;
  bool valid = (iy >= 0 && iy < 64);
  const float* xpb =
      x + (((size_t)b * NC) * 64 + (valid ? iy : 0)) * 64 + s_cq * 8;
  int xwoff = (s_r * 66 + 1 + s_cq * 8) * 48 + s_icp * 4;

  // A-frag ring (depth 3), layout [b][step=icb*9+s][oc][16]
  const uint4* wg4 = (const uint4*)wBF;
  size_t abase = (size_t)b * 144 * 512 + (size_t)(oc0 + n) * 2 + half;
  U4S8 pf[3][2];
#pragma unroll
  for (int i = 0; i < 3; ++i) {
    pf[i][0].u4 = wg4[abase + (size_t)i * 512];
    pf[i][1].u4 = wg4[abase + (size_t)i * 512 + 64];
  }

  // prologue: stage icb 0 into buf 0
  {
    float4 qa0 = make_float4(0.f, 0.f, 0.f, 0.f), qa1 = qa0, qb0 = qa0,
           qb1 = qa0;
    if (valid) {
      const float* p0 = xpb + (size_t)(s_icp * 2) * 4096;
      qa0 = *(const float4*)p0;
      qa1 = *(const float4*)(p0 + 4);
      qb0 = *(const float4*)(p0 + 4096);
      qb1 = *(const float4*)(p0 + 4100);
    }
    float av[8] = {qa0.x, qa0.y, qa0.z, qa0.w, qa1.x, qa1.y, qa1.z, qa1.w};
    float bv[8] = {qb0.x, qb0.y, qb0.z, qb0.w, qb1.x, qb1.y, qb1.z, qb1.w};
    unsigned char* xw = &ldsX[0][0] + xwoff;
#pragma unroll
    for (int j = 0; j < 8; ++j)
      *(unsigned int*)(xw + j * 48) = f2bf(av[j]) | (f2bf(bv[j]) << 16);
  }
  __syncthreads();

  for (int icb = 0; icb < 16; ++icb) {
    // issue next x-tile loads (cover = this icb's 18 mfma)
    float4 qa0 = make_float4(0.f, 0.f, 0.f, 0.f), qa1 = qa0, qb0 = qa0,
           qb1 = qa0;
    if (icb < 15 && valid) {
      const float* p0 = xpb + ((size_t)(icb + 1) * 16 + s_icp * 2) * 4096;
      qa0 = *(const float4*)p0;
      qa1 = *(const float4*)(p0 + 4);
      qb0 = *(const float4*)(p0 + 4096);
      qb1 = *(const float4*)(p0 + 4100);
    }
    const unsigned char* bufR = &ldsX[icb & 1][0];
#pragma unroll
    for (int s = 0; s < 9; ++s) {
      int step = icb * 9 + s;
      int slot = s % 3;
      int dy = s / 3, dx = s - dy * 3;
      const unsigned char* bb =
          bufR + ((pxq + dy) * 66 + pxw * 32 + n + dx) * 48 + half * 16;
      short8 B0 = *(const short8*)bb;
      acc[0] = __builtin_amdgcn_mfma_f32_32x32x16_bf16(pf[slot][0].s8, B0,
                                                       acc[0], 0, 0, 0);
      acc[1] = __builtin_amdgcn_mfma_f32_32x32x16_bf16(pf[slot][1].s8, B0,
                                                       acc[1], 0, 0, 0);
      if (step + 3 < 144) {  // refill ring slot (WAR after mfma issue)
        pf[slot][0].u4 = wg4[abase + (size_t)(step + 3) * 512];
        pf[slot][1].u4 = wg4[abase + (size_t)(step + 3) * 512 + 64];
      }
    }
    if (icb < 15) {  // convert + write next tile into other buffer
      float av[8] = {qa0.x, qa0.y, qa0.z, qa0.w, qa1.x, qa1.y, qa1.z, qa1.w};
      float bv[8] = {qb0.x, qb0.y, qb0.z, qb0.w, qb1.x, qb1.y, qb1.z, qb1.w};
      unsigned char* xw = &ldsX[(icb + 1) & 1][0] + xwoff;
#pragma unroll
      for (int j = 0; j < 8; ++j)
        *(unsigned int*)(xw + j * 48) = f2bf(av[j]) | (f2bf(bv[j]) << 16);
    }
    __syncthreads();
  }

  int py = py0 + pxq;
  int pxc = pxw * 32 + n;
#pragma unroll
  for (int osub = 0; osub < 2; ++osub) {
    int OC = oc0 + osub * 32 + 4 * half;
    float* op = out + (((size_t)(b * NC + OC)) * 64 + py) * 64 + pxc;
#pragma unroll
    for (int reg = 0; reg < 16; ++reg) {
      int ocm = (reg & 3) + 8 * (reg >> 2);
      op[(size_t)ocm * 4096] = acc[osub][reg];
    }
  }
}

extern "C" void kernel_launch(void* const* d_in, const int* in_sizes, int n_in,
                              void* d_out, int out_size, void* d_ws,
                              size_t ws_size, hipStream_t stream) {
  const float* x = (const float*)d_in[0];
  const float* dw = (const float*)d_in[1];
  const float* ka = (const float*)d_in[2];
  const int* fh = (const int*)d_in[3];
  const int* fw = (const int*)d_in[4];
  float* out = (float*)d_out;
  unsigned int* ws = (unsigned int*)d_ws;
  const unsigned short* specB = (const unsigned short*)d_ws;
  const unsigned short* Atw = (const unsigned short*)((char*)d_ws + 6291456);
  unsigned short* Ya = (unsigned short*)((char*)d_ws + 11010048);
  const unsigned short* T = (const unsigned short*)((char*)d_ws + 15925248);
  float* SW = (float*)d_ws;
  unsigned short* wBF = (unsigned short*)((char*)d_ws + WBF_BYTE);

  hipLaunchKernelGGL(prep_kernel, dim3(11364), dim3(256), 0, stream, dw, fh,
                     fw, ws);
  hipLaunchKernelGGL(fftA_kernel, dim3(12, 7, 8), dim3(256), 0, stream, Atw,
                     specB, Ya);
  hipLaunchKernelGGL(fftB_kernel, dim3(12, 12, KNUM), dim3(256), 0, stream, Ya,
                     T, SW);
  hipLaunchKernelGGL(wprep_kernel, dim3(768), dim3(256), 0, stream, ka, SW,
                     wBF);
  hipLaunchKernelGGL(conv_mfma_kernel, dim3(32, 4, NB), dim3(256), 0, stream,
                     x, wBF, out);
}

// Round 2
// 193.232 us; speedup vs baseline: 1.1228x; 1.1228x over previous
//
#include <hip/hip_runtime.h>
#include <math.h>

#define D1 768
#define D2R 385
#define NF 295680   // 768*385
#define KNUM 4
#define NB 8
#define NC 256
#define TWOPI_768 0.008181230868723419f
#define INV768 0.0013020833333333333f

// ---------------- ws layout (bytes) --------------------------------------
// specB  bf16 [4][448 c-rows][1536 k]   @ 0          (6,291,456 B)  B^T stage A
// Atw    bf16 [2][768 m][1536 k]        @ 6,291,456  (4,718,592 B)  A stage A
// Ya     bf16 [4][768 m][800 k]         @ 11,010,048 (4,915,200 B)  A stage B
// T      bf16 [768 n][800 k]            @ 15,925,248 (1,228,800 B)  B^T stage B
// SW     f32  [4][768][768]             @ 0          (9,437,184 B)  overlays specB+Atw (dead)
// wBF    bf16 [8][16][9][256][16]       @ 9,437,184  (9,437,184 B)  overlays Ya+T (dead)
#define ATW_U32 1572864u
#define YA_U32 2752512u
#define T_U32 3981312u
#define SPECB_K_U32 344064u  // 448*768 uints per k
#define WBF_BYTE 9437184u

typedef __attribute__((ext_vector_type(8))) short short8;
typedef __attribute__((ext_vector_type(16))) float f32x16;
union U4S8 { unsigned int u[4]; uint4 u4; short8 s8; };

static __device__ __forceinline__ unsigned int f2bf(float f) {
  unsigned int u = __float_as_uint(f);
  return (u + 0x7fffu + ((u >> 16) & 1u)) >> 16;  // RNE, no NaN inputs
}

// hw sin/cos: v_sin_f32/v_cos_f32 take REVOLUTIONS; idx in [0,768) -> idx/768
static __device__ __forceinline__ void sincos_rev768(int idx, float* s,
                                                     float* c) {
  float rev = (float)idx * INV768;
  *s = __builtin_amdgcn_sinf(rev);
  *c = __builtin_amdgcn_cosf(rev);
}

// ---------------- prep: scatter + twiddle matrices + zero pads -----------
__global__ __launch_bounds__(256) void prep_kernel(
    const float* __restrict__ dw, const int* __restrict__ fh,
    const int* __restrict__ fw, unsigned int* __restrict__ ws) {
  long i = (long)blockIdx.x * 256 + threadIdx.x;  // grid 11364
  if (i < 1182720) {  // scatter: dft_weight -> bf16 B^T spectrum
    int k = (int)(i / NF);
    int r = (int)(i - (long)k * NF);
    const float2 v = ((const float2*)dw)[i];
    int h = fh[r], c = fw[r];
    ws[(size_t)k * SPECB_K_U32 + (size_t)c * 768 + h] =
        f2bf(v.x) | (f2bf(v.y) << 16);
    return;
  }
  long j = i - 1182720;
  if (j < 1179648) {  // Atw: A_re/A_im [768 m][1536 k=2h]
    int ri = (int)(j / 589824);
    int rem = (int)(j - (long)ri * 589824);
    int m = rem / 768, h = rem - (rem / 768) * 768;
    int idx = (h * m) % 768;
    float s, c;
    sincos_rev768(idx, &s, &c);
    unsigned lo, hi;
    if (ri == 0) { lo = f2bf(c); hi = f2bf(-s); }
    else         { lo = f2bf(s); hi = f2bf(c); }
    ws[ATW_U32 + j] = lo | (hi << 16);
  } else if (j < 1486848) {  // T^T [768 n][800 k=2c]
    long p = j - 1179648;
    int n = (int)(p / 400), cc = (int)(p - (p / 400) * 400);
    unsigned v = 0;
    if (cc <= 384) {
      float wgt = (cc == 0 || cc == 384) ? 1.6954210069444445e-6f
                                         : 3.390842013888889e-6f;
      int idx = (cc * n) % 768;
      float s, c;
      sincos_rev768(idx, &s, &c);
      v = f2bf(wgt * c) | (f2bf(-wgt * s) << 16);
    }
    ws[T_U32 + (size_t)n * 400 + cc] = v;
  } else if (j < 1680384) {  // specB zero rows 385..447
    long p = j - 1486848;
    int k = (int)(p / 48384);
    long r = p - (long)k * 48384;
    int row = 385 + (int)(r / 768);
    int col = (int)(r - (r / 768) * 768);
    ws[(size_t)k * SPECB_K_U32 + (size_t)row * 768 + col] = 0u;
  } else if (j < 1726464) {  // Ya zero cols 770..799
    long p = j - 1680384;
    int k = (int)(p / 11520);
    long r = p - (long)k * 11520;
    int m = (int)(r / 15), jj = (int)(r - (r / 15) * 15);
    ws[YA_U32 + (size_t)k * 307200 + (size_t)m * 400 + 385 + jj] = 0u;
  }
}

// ---------------- fftA: dbuf bf16 MFMA GEMM, M=768 N=448(385) K=1536 -----
__global__ __launch_bounds__(256) void fftA_kernel(
    const unsigned short* __restrict__ Atw,
    const unsigned short* __restrict__ specB,
    unsigned short* __restrict__ Ya) {
  __shared__ __align__(16) unsigned short Al[2][64 * 40], Bl[2][64 * 40];
  int t = threadIdx.x;
  int mt = blockIdx.x, nt = blockIdx.y, z = blockIdx.z;
  int ri = z & 1, k = z >> 1;
  const unsigned short* Ag =
      Atw + (size_t)ri * 1179648 + (size_t)(mt * 64) * 1536;
  const unsigned short* Bg =
      specB + (size_t)k * 688128 + (size_t)(nt * 64) * 1536;
  int rowS = t >> 2, q = t & 3;
  int lane = t & 63, w = t >> 6;
  int moff = (w & 1) * 32, noff = (w >> 1) * 32;
  int lm = lane & 31, half = lane >> 5;
  int wr = rowS * 40 + q * 8;
  int ao = (moff + lm) * 40 + half * 8;
  int bo = (noff + lm) * 40 + half * 8;

  f32x16 acc;
#pragma unroll
  for (int r = 0; r < 16; ++r) acc[r] = 0.f;

  uint4 av = *(const uint4*)(Ag + (size_t)rowS * 1536 + q * 8);
  uint4 bv = *(const uint4*)(Bg + (size_t)rowS * 1536 + q * 8);
  *(uint4*)&Al[0][wr] = av;
  *(uint4*)&Bl[0][wr] = bv;
  __syncthreads();

  for (int kb = 0; kb < 48; ++kb) {
    bool more = (kb < 47);
    if (more) {
      av = *(const uint4*)(Ag + (size_t)rowS * 1536 + (kb + 1) * 32 + q * 8);
      bv = *(const uint4*)(Bg + (size_t)rowS * 1536 + (kb + 1) * 32 + q * 8);
    }
    const unsigned short* Ab = Al[kb & 1];
    const unsigned short* Bb = Bl[kb & 1];
#pragma unroll
    for (int kk2 = 0; kk2 < 2; ++kk2) {
      short8 a8 = *(const short8*)&Ab[ao + kk2 * 16];
      short8 b8 = *(const short8*)&Bb[bo + kk2 * 16];
      acc = __builtin_amdgcn_mfma_f32_32x32x16_bf16(a8, b8, acc, 0, 0, 0);
    }
    if (more) {
      *(uint4*)&Al[(kb + 1) & 1][wr] = av;
      *(uint4*)&Bl[(kb + 1) & 1][wr] = bv;
    }
    __syncthreads();
  }

  int c = nt * 64 + noff + lm;
  if (c < D2R) {
    unsigned short* Yk = Ya + (size_t)k * 614400;
    int mb = mt * 64 + moff + 4 * half;
#pragma unroll
    for (int reg = 0; reg < 16; ++reg) {
      int m = mb + (reg & 3) + 8 * (reg >> 2);
      Yk[(size_t)m * 800 + 2 * c + ri] = (unsigned short)f2bf(acc[reg]);
    }
  }
}

// ---------------- fftB: dbuf bf16 MFMA GEMM, M=768 N=768 K=800 -----------
__global__ __launch_bounds__(256) void fftB_kernel(
    const unsigned short* __restrict__ Ya, const unsigned short* __restrict__ T,
    float* __restrict__ SW) {
  __shared__ __align__(16) unsigned short Al[2][64 * 40], Bl[2][64 * 40];
  int t = threadIdx.x;
  int mt = blockIdx.x, nt = blockIdx.y, k = blockIdx.z;
  const unsigned short* Ag = Ya + (size_t)k * 614400 + (size_t)(mt * 64) * 800;
  const unsigned short* Bg = T + (size_t)(nt * 64) * 800;
  int rowS = t >> 2, q = t & 3;
  int lane = t & 63, w = t >> 6;
  int moff = (w & 1) * 32, noff = (w >> 1) * 32;
  int lm = lane & 31, half = lane >> 5;
  int wr = rowS * 40 + q * 8;
  int ao = (moff + lm) * 40 + half * 8;
  int bo = (noff + lm) * 40 + half * 8;

  f32x16 acc;
#pragma unroll
  for (int r = 0; r < 16; ++r) acc[r] = 0.f;

  uint4 av = *(const uint4*)(Ag + (size_t)rowS * 800 + q * 8);
  uint4 bv = *(const uint4*)(Bg + (size_t)rowS * 800 + q * 8);
  *(uint4*)&Al[0][wr] = av;
  *(uint4*)&Bl[0][wr] = bv;
  __syncthreads();

  for (int kb = 0; kb < 25; ++kb) {
    bool more = (kb < 24);
    if (more) {
      av = *(const uint4*)(Ag + (size_t)rowS * 800 + (kb + 1) * 32 + q * 8);
      bv = *(const uint4*)(Bg + (size_t)rowS * 800 + (kb + 1) * 32 + q * 8);
    }
    const unsigned short* Ab = Al[kb & 1];
    const unsigned short* Bb = Bl[kb & 1];
#pragma unroll
    for (int kk2 = 0; kk2 < 2; ++kk2) {
      short8 a8 = *(const short8*)&Ab[ao + kk2 * 16];
      short8 b8 = *(const short8*)&Bb[bo + kk2 * 16];
      acc = __builtin_amdgcn_mfma_f32_32x32x16_bf16(a8, b8, acc, 0, 0, 0);
    }
    if (more) {
      *(uint4*)&Al[(kb + 1) & 1][wr] = av;
      *(uint4*)&Bl[(kb + 1) & 1][wr] = bv;
    }
    __syncthreads();
  }

  float* SWk = SW + (size_t)k * 589824;
  int n = nt * 64 + noff + lm;
  int mb = mt * 64 + moff + 4 * half;
#pragma unroll
  for (int reg = 0; reg < 16; ++reg) {
    int m = mb + (reg & 3) + 8 * (reg >> 2);
    SWk[(size_t)m * 768 + n] = acc[reg];
  }
}

// ---------------- wprep v2: 1 block per SW row, LDS-staged coalesced -----
__global__ __launch_bounds__(256) void wprep_kernel(
    const float* __restrict__ ka, const float* __restrict__ SW,
    unsigned short* __restrict__ wBF) {
  __shared__ float rowL[4][768];
  int t = threadIdx.x;
  int row = blockIdx.x;  // grid 768: row = oc*3 + dy
  int oc = row / 3, dy = row - oc * 3;
  if (t < 192) {
#pragma unroll
    for (int k = 0; k < 4; ++k)
      *(float4*)&rowL[k][t * 4] =
          *(const float4*)(SW + (size_t)k * 589824 + (size_t)row * 768 + t * 4);
  }
  float att[8][4];
#pragma unroll
  for (int b = 0; b < 8; ++b)
#pragma unroll
    for (int k = 0; k < 4; ++k)
      att[b][k] = 0.5f / (1.f + expf(-ka[b * 4 + k]));
  __syncthreads();
  int icb = t >> 4, i = t & 15;
#pragma unroll
  for (int dx = 0; dx < 3; ++dx) {
    int col = icb * 48 + dx + 3 * i;
    float v0 = rowL[0][col], v1 = rowL[1][col], v2 = rowL[2][col],
          v3 = rowL[3][col];
    int s = dy * 3 + dx;
#pragma unroll
    for (int b = 0; b < 8; ++b) {
      float v = att[b][0] * v0 + att[b][1] * v1 + att[b][2] * v2 +
                att[b][3] * v3;
      wBF[(((size_t)(b * 16 + icb) * 9 + s) * 256 + oc) * 16 + i] =
          (unsigned short)f2bf(v);
    }
  }
}

// ---------------- conv v6: v4 tile (128oc x 2py x 64px) + ring depth 9 ---
// Post-mortem r1: oc-split doubled occupancy but halved per-step MFMA work
// between ring refill and consumption -> vmcnt stall dominated (MfmaUtil
// 28->19, dur 54->80). Revert to v4's 4-MFMA/step wave (64oc x 32px x2x2),
// deepen A-frag ring 3->9 (full icb lookahead ~1500 cyc, covers L3/HBM
// latency). slot index == s stays compile-time (no scratch spill).
__global__ __launch_bounds__(256, 2) void conv_mfma_kernel(
    const float* __restrict__ x, const unsigned short* __restrict__ wBF,
    float* __restrict__ out) {
  __shared__ __align__(16) unsigned char ldsX[2][4 * 66 * 48];
  int t = threadIdx.x;
  int pxt = blockIdx.x, oct = blockIdx.y, b = blockIdx.z;
  int py0 = pxt * 2, oc0 = oct * 128;
  int lane = t & 63, w = t >> 6;
  int ocq = w >> 1, pxq = w & 1;
  int n = lane & 31, half = lane >> 5;

  // zero halo cols (c=0,65; rows 0..3) in both buffers, once
  if (t < 192) {
    int buf = t / 96, r2 = t - buf * 96;
    int site = r2 / 12, word = r2 - site * 12;
    int r = site >> 1, c = (site & 1) ? 65 : 0;
    *(unsigned int*)(&ldsX[buf][(r * 66 + c) * 48 + word * 4]) = 0u;
  }

  f32x16 acc[2][2];
#pragma unroll
  for (int i = 0; i < 2; ++i)
#pragma unroll
    for (int j = 0; j < 2; ++j)
#pragma unroll
      for (int r = 0; r < 16; ++r) acc[i][j][r] = 0.f;

  // x staging role
  int s_cq = t >> 5, s_r = (t >> 3) & 3, s_icp = t & 7;
  int iy = py0 - 1 + s_r;
  bool valid = (iy >= 0 && iy < 64);
  const float* xpb =
      x + (((size_t)b * NC) * 64 + (valid ? iy : 0)) * 64 + s_cq * 8;
  int xwoff = (s_r * 66 + 1 + s_cq * 8) * 48 + s_icp * 4;

  // A-frag ring (depth 9 = one full icb lookahead), layout [b][step][oc][16]
  const uint4* wg4 = (const uint4*)wBF;
  size_t abase =
      (size_t)b * 144 * 512 + (size_t)(oc0 + ocq * 64 + n) * 2 + half;
  U4S8 pf[9][2];
#pragma unroll
  for (int i = 0; i < 9; ++i) {
    pf[i][0].u4 = wg4[abase + (size_t)i * 512];
    pf[i][1].u4 = wg4[abase + (size_t)i * 512 + 64];
  }

  // prologue: stage icb 0 into buf 0
  {
    float4 qa0 = make_float4(0.f, 0.f, 0.f, 0.f), qa1 = qa0, qb0 = qa0,
           qb1 = qa0;
    if (valid) {
      const float* p0 = xpb + (size_t)(s_icp * 2) * 4096;
      qa0 = *(const float4*)p0;
      qa1 = *(const float4*)(p0 + 4);
      qb0 = *(const float4*)(p0 + 4096);
      qb1 = *(const float4*)(p0 + 4100);
    }
    float av[8] = {qa0.x, qa0.y, qa0.z, qa0.w, qa1.x, qa1.y, qa1.z, qa1.w};
    float bv[8] = {qb0.x, qb0.y, qb0.z, qb0.w, qb1.x, qb1.y, qb1.z, qb1.w};
    unsigned char* xw = &ldsX[0][0] + xwoff;
#pragma unroll
    for (int j = 0; j < 8; ++j)
      *(unsigned int*)(xw + j * 48) = f2bf(av[j]) | (f2bf(bv[j]) << 16);
  }
  __syncthreads();

  for (int icb = 0; icb < 16; ++icb) {
    // issue next x-tile loads (cover = this icb's 36 mfma)
    float4 qa0 = make_float4(0.f, 0.f, 0.f, 0.f), qa1 = qa0, qb0 = qa0,
           qb1 = qa0;
    if (icb < 15 && valid) {
      const float* p0 = xpb + ((size_t)(icb + 1) * 16 + s_icp * 2) * 4096;
      qa0 = *(const float4*)p0;
      qa1 = *(const float4*)(p0 + 4);
      qb0 = *(const float4*)(p0 + 4096);
      qb1 = *(const float4*)(p0 + 4100);
    }
    const unsigned char* bufR = &ldsX[icb & 1][0];
#pragma unroll
    for (int s = 0; s < 9; ++s) {
      int step = icb * 9 + s;
      int dy = s / 3, dx = s - dy * 3;
      const unsigned char* bb =
          bufR + ((pxq + dy) * 66 + n + dx) * 48 + half * 16;
      short8 B0 = *(const short8*)bb;
      short8 B1 = *(const short8*)(bb + 32 * 48);
      acc[0][0] = __builtin_amdgcn_mfma_f32_32x32x16_bf16(pf[s][0].s8, B0,
                                                          acc[0][0], 0, 0, 0);
      acc[0][1] = __builtin_amdgcn_mfma_f32_32x32x16_bf16(pf[s][0].s8, B1,
                                                          acc[0][1], 0, 0, 0);
      acc[1][0] = __builtin_amdgcn_mfma_f32_32x32x16_bf16(pf[s][1].s8, B0,
                                                          acc[1][0], 0, 0, 0);
      acc[1][1] = __builtin_amdgcn_mfma_f32_32x32x16_bf16(pf[s][1].s8, B1,
                                                          acc[1][1], 0, 0, 0);
      if (icb < 15) {  // refill ring slot s for next icb (WAR after mfma)
        pf[s][0].u4 = wg4[abase + (size_t)(step + 9) * 512];
        pf[s][1].u4 = wg4[abase + (size_t)(step + 9) * 512 + 64];
      }
    }
    if (icb < 15) {  // convert + write next tile into other buffer
      float av[8] = {qa0.x, qa0.y, qa0.z, qa0.w, qa1.x, qa1.y, qa1.z, qa1.w};
      float bv[8] = {qb0.x, qb0.y, qb0.z, qb0.w, qb1.x, qb1.y, qb1.z, qb1.w};
      unsigned char* xw = &ldsX[(icb + 1) & 1][0] + xwoff;
#pragma unroll
      for (int j = 0; j < 8; ++j)
        *(unsigned int*)(xw + j * 48) = f2bf(av[j]) | (f2bf(bv[j]) << 16);
    }
    __syncthreads();
  }

  int py = py0 + pxq;
#pragma unroll
  for (int osub = 0; osub < 2; ++osub)
#pragma unroll
    for (int psub = 0; psub < 2; ++psub) {
      int OC = oc0 + ocq * 64 + osub * 32 + 4 * half;
      int pxc = psub * 32 + n;
      float* op = out + (((size_t)(b * NC + OC)) * 64 + py) * 64 + pxc;
#pragma unroll
      for (int reg = 0; reg < 16; ++reg) {
        int ocm = (reg & 3) + 8 * (reg >> 2);
        op[(size_t)ocm * 4096] = acc[osub][psub][reg];
      }
    }
}

extern "C" void kernel_launch(void* const* d_in, const int* in_sizes, int n_in,
                              void* d_out, int out_size, void* d_ws,
                              size_t ws_size, hipStream_t stream) {
  const float* x = (const float*)d_in[0];
  const float* dw = (const float*)d_in[1];
  const float* ka = (const float*)d_in[2];
  const int* fh = (const int*)d_in[3];
  const int* fw = (const int*)d_in[4];
  float* out = (float*)d_out;
  unsigned int* ws = (unsigned int*)d_ws;
  const unsigned short* specB = (const unsigned short*)d_ws;
  const unsigned short* Atw = (const unsigned short*)((char*)d_ws + 6291456);
  unsigned short* Ya = (unsigned short*)((char*)d_ws + 11010048);
  const unsigned short* T = (const unsigned short*)((char*)d_ws + 15925248);
  float* SW = (float*)d_ws;
  unsigned short* wBF = (unsigned short*)((char*)d_ws + WBF_BYTE);

  hipLaunchKernelGGL(prep_kernel, dim3(11364), dim3(256), 0, stream, dw, fh,
                     fw, ws);
  hipLaunchKernelGGL(fftA_kernel, dim3(12, 7, 8), dim3(256), 0, stream, Atw,
                     specB, Ya);
  hipLaunchKernelGGL(fftB_kernel, dim3(12, 12, KNUM), dim3(256), 0, stream, Ya,
                     T, SW);
  hipLaunchKernelGGL(wprep_kernel, dim3(768), dim3(256), 0, stream, ka, SW,
                     wBF);
  hipLaunchKernelGGL(conv_mfma_kernel, dim3(32, 2, NB), dim3(256), 0, stream,
                     x, wBF, out);
}

// Round 3
// 192.657 us; speedup vs baseline: 1.1261x; 1.0030x over previous
//
#include <hip/hip_runtime.h>
#include <math.h>

#define D1 768
#define D2R 385
#define NF 295680   // 768*385
#define KNUM 4
#define NB 8
#define NC 256
#define TWOPI_768 0.008181230868723419f
#define INV768 0.0013020833333333333f

// ---------------- ws layout (bytes) --------------------------------------
// specB  bf16 [4][448 c-rows][1536 k]   @ 0          (6,291,456 B)  B^T stage A
// Atw    bf16 [2][768 m][1536 k]        @ 6,291,456  (4,718,592 B)  A stage A
// Ya     bf16 [4][768 m][800 k]         @ 11,010,048 (4,915,200 B)  A stage B
// T      bf16 [768 n][800 k]            @ 15,925,248 (1,228,800 B)  B^T stage B
// SW     f32  [4][768][768]             @ 0          (9,437,184 B)  overlays specB+Atw (dead)
// wBF    bf16 [8][16][9][256][16]       @ 9,437,184  (9,437,184 B)  overlays Ya+T (dead)
#define ATW_U32 1572864u
#define YA_U32 2752512u
#define T_U32 3981312u
#define SPECB_K_U32 344064u  // 448*768 uints per k
#define WBF_BYTE 9437184u

typedef __attribute__((ext_vector_type(8))) short short8;
typedef __attribute__((ext_vector_type(16))) float f32x16;
typedef __attribute__((ext_vector_type(4))) float f4;
union U4S8 { unsigned int u[4]; uint4 u4; short8 s8; };

static __device__ __forceinline__ unsigned int f2bf(float f) {
  unsigned int u = __float_as_uint(f);
  return (u + 0x7fffu + ((u >> 16) & 1u)) >> 16;  // RNE, no NaN inputs
}

// hw sin/cos: v_sin_f32/v_cos_f32 take REVOLUTIONS; idx in [0,768) -> idx/768
static __device__ __forceinline__ void sincos_rev768(int idx, float* s,
                                                     float* c) {
  float rev = (float)idx * INV768;
  *s = __builtin_amdgcn_sinf(rev);
  *c = __builtin_amdgcn_cosf(rev);
}

// raw barrier: LDS-drain only; register-dest vmem loads stay in flight
// (avoids __syncthreads' s_waitcnt vmcnt(0) drain of prefetch loads).
// sched_barrier(0) pins ordering (rule: compiler may move LDS ops across
// the IntrNoMem s_barrier intrinsic otherwise).
static __device__ __forceinline__ void barrier_lgkm() {
  asm volatile("s_waitcnt lgkmcnt(0)" ::: "memory");
  __builtin_amdgcn_sched_barrier(0);
  __builtin_amdgcn_s_barrier();
  __builtin_amdgcn_sched_barrier(0);
}

// ---------------- prep: scatter + twiddle matrices + zero pads -----------
__global__ __launch_bounds__(256) void prep_kernel(
    const float* __restrict__ dw, const int* __restrict__ fh,
    const int* __restrict__ fw, unsigned int* __restrict__ ws) {
  long i = (long)blockIdx.x * 256 + threadIdx.x;  // grid 11364
  if (i < 1182720) {  // scatter: dft_weight -> bf16 B^T spectrum
    int k = (int)(i / NF);
    int r = (int)(i - (long)k * NF);
    const float2 v = ((const float2*)dw)[i];
    int h = fh[r], c = fw[r];
    ws[(size_t)k * SPECB_K_U32 + (size_t)c * 768 + h] =
        f2bf(v.x) | (f2bf(v.y) << 16);
    return;
  }
  long j = i - 1182720;
  if (j < 1179648) {  // Atw: A_re/A_im [768 m][1536 k=2h]
    int ri = (int)(j / 589824);
    int rem = (int)(j - (long)ri * 589824);
    int m = rem / 768, h = rem - (rem / 768) * 768;
    int idx = (h * m) % 768;
    float s, c;
    sincos_rev768(idx, &s, &c);
    unsigned lo, hi;
    if (ri == 0) { lo = f2bf(c); hi = f2bf(-s); }
    else         { lo = f2bf(s); hi = f2bf(c); }
    ws[ATW_U32 + j] = lo | (hi << 16);
  } else if (j < 1486848) {  // T^T [768 n][800 k=2c]
    long p = j - 1179648;
    int n = (int)(p / 400), cc = (int)(p - (p / 400) * 400);
    unsigned v = 0;
    if (cc <= 384) {
      float wgt = (cc == 0 || cc == 384) ? 1.6954210069444445e-6f
                                         : 3.390842013888889e-6f;
      int idx = (cc * n) % 768;
      float s, c;
      sincos_rev768(idx, &s, &c);
      v = f2bf(wgt * c) | (f2bf(-wgt * s) << 16);
    }
    ws[T_U32 + (size_t)n * 400 + cc] = v;
  } else if (j < 1680384) {  // specB zero rows 385..447
    long p = j - 1486848;
    int k = (int)(p / 48384);
    long r = p - (long)k * 48384;
    int row = 385 + (int)(r / 768);
    int col = (int)(r - (r / 768) * 768);
    ws[(size_t)k * SPECB_K_U32 + (size_t)row * 768 + col] = 0u;
  } else if (j < 1726464) {  // Ya zero cols 770..799
    long p = j - 1680384;
    int k = (int)(p / 11520);
    long r = p - (long)k * 11520;
    int m = (int)(r / 15), jj = (int)(r - (r / 15) * 15);
    ws[YA_U32 + (size_t)k * 307200 + (size_t)m * 400 + 385 + jj] = 0u;
  }
}

// ---------------- fftA: dbuf bf16 MFMA GEMM, M=768 N=448(385) K=1536 -----
__global__ __launch_bounds__(256) void fftA_kernel(
    const unsigned short* __restrict__ Atw,
    const unsigned short* __restrict__ specB,
    unsigned short* __restrict__ Ya) {
  __shared__ __align__(16) unsigned short Al[2][64 * 40], Bl[2][64 * 40];
  int t = threadIdx.x;
  int mt = blockIdx.x, nt = blockIdx.y, z = blockIdx.z;
  int ri = z & 1, k = z >> 1;
  const unsigned short* Ag =
      Atw + (size_t)ri * 1179648 + (size_t)(mt * 64) * 1536;
  const unsigned short* Bg =
      specB + (size_t)k * 688128 + (size_t)(nt * 64) * 1536;
  int rowS = t >> 2, q = t & 3;
  int lane = t & 63, w = t >> 6;
  int moff = (w & 1) * 32, noff = (w >> 1) * 32;
  int lm = lane & 31, half = lane >> 5;
  int wr = rowS * 40 + q * 8;
  int ao = (moff + lm) * 40 + half * 8;
  int bo = (noff + lm) * 40 + half * 8;

  f32x16 acc;
#pragma unroll
  for (int r = 0; r < 16; ++r) acc[r] = 0.f;

  uint4 av = *(const uint4*)(Ag + (size_t)rowS * 1536 + q * 8);
  uint4 bv = *(const uint4*)(Bg + (size_t)rowS * 1536 + q * 8);
  *(uint4*)&Al[0][wr] = av;
  *(uint4*)&Bl[0][wr] = bv;
  __syncthreads();

  for (int kb = 0; kb < 48; ++kb) {
    bool more = (kb < 47);
    if (more) {
      av = *(const uint4*)(Ag + (size_t)rowS * 1536 + (kb + 1) * 32 + q * 8);
      bv = *(const uint4*)(Bg + (size_t)rowS * 1536 + (kb + 1) * 32 + q * 8);
    }
    const unsigned short* Ab = Al[kb & 1];
    const unsigned short* Bb = Bl[kb & 1];
#pragma unroll
    for (int kk2 = 0; kk2 < 2; ++kk2) {
      short8 a8 = *(const short8*)&Ab[ao + kk2 * 16];
      short8 b8 = *(const short8*)&Bb[bo + kk2 * 16];
      acc = __builtin_amdgcn_mfma_f32_32x32x16_bf16(a8, b8, acc, 0, 0, 0);
    }
    if (more) {
      *(uint4*)&Al[(kb + 1) & 1][wr] = av;
      *(uint4*)&Bl[(kb + 1) & 1][wr] = bv;
    }
    __syncthreads();
  }

  int c = nt * 64 + noff + lm;
  if (c < D2R) {
    unsigned short* Yk = Ya + (size_t)k * 614400;
    int mb = mt * 64 + moff + 4 * half;
#pragma unroll
    for (int reg = 0; reg < 16; ++reg) {
      int m = mb + (reg & 3) + 8 * (reg >> 2);
      Yk[(size_t)m * 800 + 2 * c + ri] = (unsigned short)f2bf(acc[reg]);
    }
  }
}

// ---------------- fftB: dbuf bf16 MFMA GEMM, M=768 N=768 K=800 -----------
__global__ __launch_bounds__(256) void fftB_kernel(
    const unsigned short* __restrict__ Ya, const unsigned short* __restrict__ T,
    float* __restrict__ SW) {
  __shared__ __align__(16) unsigned short Al[2][64 * 40], Bl[2][64 * 40];
  int t = threadIdx.x;
  int mt = blockIdx.x, nt = blockIdx.y, k = blockIdx.z;
  const unsigned short* Ag = Ya + (size_t)k * 614400 + (size_t)(mt * 64) * 800;
  const unsigned short* Bg = T + (size_t)(nt * 64) * 800;
  int rowS = t >> 2, q = t & 3;
  int lane = t & 63, w = t >> 6;
  int moff = (w & 1) * 32, noff = (w >> 1) * 32;
  int lm = lane & 31, half = lane >> 5;
  int wr = rowS * 40 + q * 8;
  int ao = (moff + lm) * 40 + half * 8;
  int bo = (noff + lm) * 40 + half * 8;

  f32x16 acc;
#pragma unroll
  for (int r = 0; r < 16; ++r) acc[r] = 0.f;

  uint4 av = *(const uint4*)(Ag + (size_t)rowS * 800 + q * 8);
  uint4 bv = *(const uint4*)(Bg + (size_t)rowS * 800 + q * 8);
  *(uint4*)&Al[0][wr] = av;
  *(uint4*)&Bl[0][wr] = bv;
  __syncthreads();

  for (int kb = 0; kb < 25; ++kb) {
    bool more = (kb < 24);
    if (more) {
      av = *(const uint4*)(Ag + (size_t)rowS * 800 + (kb + 1) * 32 + q * 8);
      bv = *(const uint4*)(Bg + (size_t)rowS * 800 + (kb + 1) * 32 + q * 8);
    }
    const unsigned short* Ab = Al[kb & 1];
    const unsigned short* Bb = Bl[kb & 1];
#pragma unroll
    for (int kk2 = 0; kk2 < 2; ++kk2) {
      short8 a8 = *(const short8*)&Ab[ao + kk2 * 16];
      short8 b8 = *(const short8*)&Bb[bo + kk2 * 16];
      acc = __builtin_amdgcn_mfma_f32_32x32x16_bf16(a8, b8, acc, 0, 0, 0);
    }
    if (more) {
      *(uint4*)&Al[(kb + 1) & 1][wr] = av;
      *(uint4*)&Bl[(kb + 1) & 1][wr] = bv;
    }
    __syncthreads();
  }

  float* SWk = SW + (size_t)k * 589824;
  int n = nt * 64 + noff + lm;
  int mb = mt * 64 + moff + 4 * half;
#pragma unroll
  for (int reg = 0; reg < 16; ++reg) {
    int m = mb + (reg & 3) + 8 * (reg >> 2);
    SWk[(size_t)m * 768 + n] = acc[reg];
  }
}

// ---------------- wprep v2: 1 block per SW row, LDS-staged coalesced -----
__global__ __launch_bounds__(256) void wprep_kernel(
    const float* __restrict__ ka, const float* __restrict__ SW,
    unsigned short* __restrict__ wBF) {
  __shared__ float rowL[4][768];
  int t = threadIdx.x;
  int row = blockIdx.x;  // grid 768: row = oc*3 + dy
  int oc = row / 3, dy = row - oc * 3;
  if (t < 192) {
#pragma unroll
    for (int k = 0; k < 4; ++k)
      *(float4*)&rowL[k][t * 4] =
          *(const float4*)(SW + (size_t)k * 589824 + (size_t)row * 768 + t * 4);
  }
  float att[8][4];
#pragma unroll
  for (int b = 0; b < 8; ++b)
#pragma unroll
    for (int k = 0; k < 4; ++k)
      att[b][k] = 0.5f / (1.f + expf(-ka[b * 4 + k]));
  __syncthreads();
  int icb = t >> 4, i = t & 15;
#pragma unroll
  for (int dx = 0; dx < 3; ++dx) {
    int col = icb * 48 + dx + 3 * i;
    float v0 = rowL[0][col], v1 = rowL[1][col], v2 = rowL[2][col],
          v3 = rowL[3][col];
    int s = dy * 3 + dx;
#pragma unroll
    for (int b = 0; b < 8; ++b) {
      float v = att[b][0] * v0 + att[b][1] * v1 + att[b][2] * v2 +
                att[b][3] * v3;
      wBF[(((size_t)(b * 16 + icb) * 9 + s) * 256 + oc) * 16 + i] =
          (unsigned short)f2bf(v);
    }
  }
}

// coalesced x stage: pack thread's 4 ic-rows (4 px each) into bf16 pairs
static __device__ __forceinline__ void stage_write(unsigned char* xw, f4 v0,
                                                   f4 v1, f4 v2, f4 v3) {
#pragma unroll
  for (int pp = 0; pp < 4; ++pp) {
    uint2 wv;
    wv.x = f2bf(v0[pp]) | (f2bf(v1[pp]) << 16);
    wv.y = f2bf(v2[pp]) | (f2bf(v3[pp]) << 16);
    *(uint2*)(xw + pp * 48) = wv;
  }
}

// ---------------- conv v7: coalesced x staging + lgkm-only barrier -------
// r2 post-mortem: 8100 cyc/icb/CU measured; MFMA floor 2304 (=28% util,
// matches counter). Dominant stall = TA line-requests: old x staging put
// adjacent lanes on different ic (16KB apart) -> 64 lines per wave-load,
// 4096 lines/CU/icb vs 2304 MFMA cyc. New mapping: lane=sub*16+px4 reads
// 1KB contiguous per wave-load (16 lines) -> 512 lines/CU/icb. Transpose
// ic<->px moved to LDS write (4x ds_write_b64, layout unchanged for reads).
// Barrier: lgkmcnt(0)-only raw s_barrier keeps 18 pf refills + 4 x loads
// in flight (no vmcnt(0) drain per icb).
__global__ __launch_bounds__(256, 2) void conv_mfma_kernel(
    const float* __restrict__ x, const unsigned short* __restrict__ wBF,
    float* __restrict__ out) {
  __shared__ __align__(16) unsigned char ldsX[2][4 * 66 * 48];
  int t = threadIdx.x;
  int pxt = blockIdx.x, oct = blockIdx.y, b = blockIdx.z;
  int py0 = pxt * 2, oc0 = oct * 128;
  int lane = t & 63, w = t >> 6;
  int ocq = w >> 1, pxq = w & 1;
  int n = lane & 31, half = lane >> 5;

  // zero halo cols (c=0,65; rows 0..3) in both buffers, once
  if (t < 192) {
    int buf = t / 96, r2 = t - buf * 96;
    int site = r2 / 12, word = r2 - site * 12;
    int r = site >> 1, c = (site & 1) ? 65 : 0;
    *(unsigned int*)(&ldsX[buf][(r * 66 + c) * 48 + word * 4]) = 0u;
  }

  f32x16 acc[2][2];
#pragma unroll
  for (int i = 0; i < 2; ++i)
#pragma unroll
    for (int j = 0; j < 2; ++j)
#pragma unroll
      for (int r = 0; r < 16; ++r) acc[i][j][r] = 0.f;

  // coalesced x staging role: lane = sub*16 + px4; wave w covers tile-ic
  // w*4..w*4+3. One wave-load = 4 consecutive rows x 256B = 1KB contiguous.
  int px4 = lane & 15, sub = lane >> 4;
  int iy = py0 - 1 + sub;
  bool valid = (iy >= 0 && iy < 64);
  const float* xpb =
      x + (((size_t)(b * NC + w * 4)) * 64 + (valid ? iy : 0)) * 64 + px4 * 4;
  int xwbase = (sub * 66 + 1 + px4 * 4) * 48 + w * 8;

  // issue x tile 0 loads FIRST (oldest in vmem queue), so waiting on them
  // at the LDS write leaves the 18 pf ring loads outstanding.
  f4 a0 = {0.f, 0.f, 0.f, 0.f}, a1 = a0, a2 = a0, a3 = a0;
  if (valid) {
    const float* p0 = xpb;  // ic = w*4 + j, tile 0
    a0 = *(const f4*)(p0);
    a1 = *(const f4*)(p0 + 4096);
    a2 = *(const f4*)(p0 + 8192);
    a3 = *(const f4*)(p0 + 12288);
  }

  // A-frag ring (depth 9 = one full icb lookahead), layout [b][step][oc][16]
  const uint4* wg4 = (const uint4*)wBF;
  size_t abase =
      (size_t)b * 144 * 512 + (size_t)(oc0 + ocq * 64 + n) * 2 + half;
  U4S8 pf[9][2];
#pragma unroll
  for (int i = 0; i < 9; ++i) {
    pf[i][0].u4 = wg4[abase + (size_t)i * 512];
    pf[i][1].u4 = wg4[abase + (size_t)i * 512 + 64];
  }

  stage_write(&ldsX[0][0] + xwbase, a0, a1, a2, a3);
  barrier_lgkm();

  for (int icb = 0; icb < 16; ++icb) {
    // issue next x-tile loads (coalesced; cover = this icb's 36 mfma)
    a0 = a1 = a2 = a3 = (f4){0.f, 0.f, 0.f, 0.f};
    if (icb < 15 && valid) {
      const float* p0 = xpb + (size_t)(icb + 1) * 16 * 4096;
      a0 = *(const f4*)(p0);
      a1 = *(const f4*)(p0 + 4096);
      a2 = *(const f4*)(p0 + 8192);
      a3 = *(const f4*)(p0 + 12288);
    }
    const unsigned char* bufR = &ldsX[icb & 1][0];
#pragma unroll
    for (int s = 0; s < 9; ++s) {
      int step = icb * 9 + s;
      int dy = s / 3, dx = s - dy * 3;
      const unsigned char* bb =
          bufR + ((pxq + dy) * 66 + n + dx) * 48 + half * 16;
      short8 B0 = *(const short8*)bb;
      short8 B1 = *(const short8*)(bb + 32 * 48);
      acc[0][0] = __builtin_amdgcn_mfma_f32_32x32x16_bf16(pf[s][0].s8, B0,
                                                          acc[0][0], 0, 0, 0);
      acc[0][1] = __builtin_amdgcn_mfma_f32_32x32x16_bf16(pf[s][0].s8, B1,
                                                          acc[0][1], 0, 0, 0);
      acc[1][0] = __builtin_amdgcn_mfma_f32_32x32x16_bf16(pf[s][1].s8, B0,
                                                          acc[1][0], 0, 0, 0);
      acc[1][1] = __builtin_amdgcn_mfma_f32_32x32x16_bf16(pf[s][1].s8, B1,
                                                          acc[1][1], 0, 0, 0);
      if (icb < 15) {  // refill ring slot s for next icb (WAR after mfma)
        pf[s][0].u4 = wg4[abase + (size_t)(step + 9) * 512];
        pf[s][1].u4 = wg4[abase + (size_t)(step + 9) * 512 + 64];
      }
    }
    if (icb < 15)  // convert + write next tile into other buffer
      stage_write(&ldsX[(icb + 1) & 1][0] + xwbase, a0, a1, a2, a3);
    barrier_lgkm();
  }

  int py = py0 + pxq;
#pragma unroll
  for (int osub = 0; osub < 2; ++osub)
#pragma unroll
    for (int psub = 0; psub < 2; ++psub) {
      int OC = oc0 + ocq * 64 + osub * 32 + 4 * half;
      int pxc = psub * 32 + n;
      float* op = out + (((size_t)(b * NC + OC)) * 64 + py) * 64 + pxc;
#pragma unroll
      for (int reg = 0; reg < 16; ++reg) {
        int ocm = (reg & 3) + 8 * (reg >> 2);
        op[(size_t)ocm * 4096] = acc[osub][psub][reg];
      }
    }
}

extern "C" void kernel_launch(void* const* d_in, const int* in_sizes, int n_in,
                              void* d_out, int out_size, void* d_ws,
                              size_t ws_size, hipStream_t stream) {
  const float* x = (const float*)d_in[0];
  const float* dw = (const float*)d_in[1];
  const float* ka = (const float*)d_in[2];
  const int* fh = (const int*)d_in[3];
  const int* fw = (const int*)d_in[4];
  float* out = (float*)d_out;
  unsigned int* ws = (unsigned int*)d_ws;
  const unsigned short* specB = (const unsigned short*)d_ws;
  const unsigned short* Atw = (const unsigned short*)((char*)d_ws + 6291456);
  unsigned short* Ya = (unsigned short*)((char*)d_ws + 11010048);
  const unsigned short* T = (const unsigned short*)((char*)d_ws + 15925248);
  float* SW = (float*)d_ws;
  unsigned short* wBF = (unsigned short*)((char*)d_ws + WBF_BYTE);

  hipLaunchKernelGGL(prep_kernel, dim3(11364), dim3(256), 0, stream, dw, fh,
                     fw, ws);
  hipLaunchKernelGGL(fftA_kernel, dim3(12, 7, 8), dim3(256), 0, stream, Atw,
                     specB, Ya);
  hipLaunchKernelGGL(fftB_kernel, dim3(12, 12, KNUM), dim3(256), 0, stream, Ya,
                     T, SW);
  hipLaunchKernelGGL(wprep_kernel, dim3(768), dim3(256), 0, stream, ka, SW,
                     wBF);
  hipLaunchKernelGGL(conv_mfma_kernel, dim3(32, 2, NB), dim3(256), 0, stream,
                     x, wBF, out);
}